// Round 1
// baseline (805.664 us; speedup 1.0000x reference)
//
#include <hip/hip_runtime.h>
#include <hip/hip_bf16.h>
#include <stdint.h>

typedef _Float16 f16x8 __attribute__((ext_vector_type(8)));
typedef float f32x4 __attribute__((ext_vector_type(4)));

#define MFMA_F16(A, B, C) __builtin_amdgcn_mfma_f32_16x16x32_f16(A, B, C, 0, 0, 0)

constexpr int Bb = 4, Nn = 4096, Cc = 256;
constexpr int BQ = 64;           // q rows per block (4 waves x 16) -> 512 blocks, 2/CU
constexpr int BK = 64;           // k/v rows per tile
constexpr int NT = Nn / BK;
constexpr int KPAD = 264;        // fp16 elems; 528B row stride (16B-mult, conflict-free)
constexpr int VPAD = 72;         // 144B row stride
constexpr int PPAD = 72;

constexpr size_t ASZ = (size_t)2 * Bb * Nn * Cc;     // elems per ws array
constexpr size_t WS_NEED = ASZ * 2 * 3;              // bytes: hi + lo + vt

// ---------------- prep: fp32 -> fp16 hi/lo + transposed hi ----------------
__global__ __launch_bounds__(256)
void prep_kernel(const float* __restrict__ xa, const float* __restrict__ xb,
                 _Float16* __restrict__ hi, _Float16* __restrict__ lo,
                 _Float16* __restrict__ vt)
{
    const int n0 = blockIdx.x * 64, c0 = blockIdx.y * 64, ib = blockIdx.z;
    const float* x = ((ib >> 2) == 0 ? xa : xb) + (size_t)(ib & 3) * Nn * Cc;
    const size_t base = (size_t)ib * Nn * Cc;
    __shared__ ushort tile[64][68];
    const int t = threadIdx.x;
    const int r0 = t >> 4;            // 0..15
    const int c4 = (t & 15) * 4;      // 0,4,..,60
    #pragma unroll
    for (int ii = 0; ii < 4; ++ii) {
        const int r = r0 + ii * 16;
        float4 v = *(const float4*)&x[(size_t)(n0 + r) * Cc + c0 + c4];
        float vv[4] = {v.x, v.y, v.z, v.w};
        union { _Float16 h[4]; uint2 q; } H, L;
        #pragma unroll
        for (int e = 0; e < 4; ++e) {
            _Float16 h = (_Float16)vv[e];
            H.h[e] = h;
            L.h[e] = (_Float16)(vv[e] - (float)h);
        }
        *(uint2*)&hi[base + (size_t)(n0 + r) * Cc + c0 + c4] = H.q;
        *(uint2*)&lo[base + (size_t)(n0 + r) * Cc + c0 + c4] = L.q;
        *(uint2*)&tile[r][c4] = H.q;
    }
    __syncthreads();
    const int j4 = (t & 15) * 4;
    #pragma unroll
    for (int ii = 0; ii < 4; ++ii) {
        const int cr = r0 + ii * 16;
        ushort4 o;
        o.x = tile[j4 + 0][cr]; o.y = tile[j4 + 1][cr];
        o.z = tile[j4 + 2][cr]; o.w = tile[j4 + 3][cr];
        *(ushort4*)&vt[base + (size_t)(c0 + cr) * Nn + n0 + j4] = o;
    }
}

// ---------------- main attention ----------------
template<bool PREP>
__global__ __launch_bounds__(256, 2)
void attn_kernel(const float* __restrict__ xa, const float* __restrict__ xb,
                 const float* __restrict__ gamma_p, float* __restrict__ out,
                 const _Float16* __restrict__ hi, const _Float16* __restrict__ lo,
                 const _Float16* __restrict__ vt)
{
    const int qtile = blockIdx.x, b = blockIdx.y, dir = blockIdx.z;
    const float* qsrc = (dir == 0 ? xa : xb) + (size_t)b * Nn * Cc;
    const float* ksrc = (dir == 0 ? xb : xa) + (size_t)b * Nn * Cc;
    float* outp = out + (size_t)dir * Bb * Nn * Cc + (size_t)b * Nn * Cc;
    const int qib = dir * Bb + b;
    const int kib = (dir ^ 1) * Bb + b;
    const _Float16* qhiB = hi + (size_t)qib * Nn * Cc;
    const _Float16* qloB = lo + (size_t)qib * Nn * Cc;
    const _Float16* kB   = hi + (size_t)kib * Nn * Cc;
    const _Float16* vtB  = vt + (size_t)qib * Nn * Cc;   // V^T of q-source

    __shared__ _Float16 sK[BK][KPAD];       // K (fp16 hi), rows m
    __shared__ _Float16 sVt[Cc][VPAD];      // sVt[c][m] = V[m][c]
    __shared__ _Float16 sP[4][16][PPAD];    // per-wave P tile [qrow][m]

    const int t = threadIdx.x, lane = t & 63, w = t >> 6;
    const int l15 = lane & 15, g = lane >> 4;
    const int khalf = g * 8;

    // ---- Q fragments, negated (MFMA yields logits = -E), fp16 hi/lo ----
    f16x8 qhi[8], qlo[8];
    const int qrow = qtile * BQ + w * 16 + l15;
    if constexpr (PREP) {
        #pragma unroll
        for (int j = 0; j < 8; ++j) {
            union { uint4 u; f16x8 h; } A, C2;
            A.u  = *(const uint4*)(qhiB + (size_t)qrow * Cc + j * 32 + khalf);
            C2.u = *(const uint4*)(qloB + (size_t)qrow * Cc + j * 32 + khalf);
            A.u.x ^= 0x80008000u; A.u.y ^= 0x80008000u; A.u.z ^= 0x80008000u; A.u.w ^= 0x80008000u;
            C2.u.x ^= 0x80008000u; C2.u.y ^= 0x80008000u; C2.u.z ^= 0x80008000u; C2.u.w ^= 0x80008000u;
            qhi[j] = A.h; qlo[j] = C2.h;
        }
    } else {
        const float* qb = qsrc + (size_t)qrow * Cc;
        #pragma unroll
        for (int j = 0; j < 8; ++j) {
            float4 v0 = *(const float4*)(qb + j * 32 + khalf);
            float4 v1 = *(const float4*)(qb + j * 32 + khalf + 4);
            float xv[8] = {v0.x, v0.y, v0.z, v0.w, v1.x, v1.y, v1.z, v1.w};
            #pragma unroll
            for (int e = 0; e < 8; ++e) {
                float xn = -xv[e];
                _Float16 h = (_Float16)xn;
                qhi[j][e] = h;
                qlo[j][e] = (_Float16)(xn - (float)h);
            }
        }
    }

    f32x4 O[16];
    #pragma unroll
    for (int i = 0; i < 16; ++i) O[i] = (f32x4){0.f, 0.f, 0.f, 0.f};
    float mrow[4] = {-INFINITY, -INFINITY, -INFINITY, -INFINITY};
    float lsum[4] = {0.f, 0.f, 0.f, 0.f};

    // staging maps (256 threads): K: 64 rows x 4 col-chunks of 64; Vt: 256 rows x 64 m
    const int kr = t & 63, kc = (t >> 6) * 64;     // K: row, col-chunk
    const int vr = t;                              // Vt: row (=channel)
    uint4 kreg[8], vreg[8];

    auto loadRegs = [&](int m0) {
        const _Float16* kg = kB + (size_t)(m0 + kr) * Cc + kc;
        #pragma unroll
        for (int q = 0; q < 8; ++q) kreg[q] = *(const uint4*)(kg + q * 8);
        const _Float16* vg = vtB + (size_t)vr * Nn + m0;
        #pragma unroll
        for (int q = 0; q < 8; ++q) vreg[q] = *(const uint4*)(vg + q * 8);
    };
    auto writeLDS = [&]() {
        #pragma unroll
        for (int q = 0; q < 8; ++q) *(uint4*)&sK[kr][kc + q * 8] = kreg[q];
        #pragma unroll
        for (int q = 0; q < 8; ++q) *(uint4*)&sVt[vr][q * 8] = vreg[q];
    };

    auto compute = [&]() {
        // ---- S = (-Q) K^T : q split fp16 hi/lo, k single fp16 ----
        f32x4 S[4];
        #pragma unroll
        for (int s = 0; s < 4; ++s) S[s] = (f32x4){0.f, 0.f, 0.f, 0.f};
        __builtin_amdgcn_s_setprio(1);
        #pragma unroll
        for (int j = 0; j < 8; ++j) {
            const int ko = j * 32 + khalf;
            f16x8 k0 = *(const f16x8*)&sK[l15][ko];
            f16x8 k1 = *(const f16x8*)&sK[16 + l15][ko];
            f16x8 k2 = *(const f16x8*)&sK[32 + l15][ko];
            f16x8 k3 = *(const f16x8*)&sK[48 + l15][ko];
            S[0] = MFMA_F16(qhi[j], k0, S[0]);
            S[1] = MFMA_F16(qhi[j], k1, S[1]);
            S[2] = MFMA_F16(qhi[j], k2, S[2]);
            S[3] = MFMA_F16(qhi[j], k3, S[3]);
            S[0] = MFMA_F16(qlo[j], k0, S[0]);
            S[1] = MFMA_F16(qlo[j], k1, S[1]);
            S[2] = MFMA_F16(qlo[j], k2, S[2]);
            S[3] = MFMA_F16(qlo[j], k3, S[3]);
        }
        __builtin_amdgcn_s_setprio(0);

        // ---- online softmax: per-tile max reduce; sum deferred to epilogue ----
        float tmax4[4];
        bool need = false;
        #pragma unroll
        for (int r = 0; r < 4; ++r) {
            float tm = fmaxf(fmaxf(S[0][r], S[1][r]), fmaxf(S[2][r], S[3][r]));
            #pragma unroll
            for (int off = 8; off >= 1; off >>= 1)
                tm = fmaxf(tm, __shfl_xor(tm, off, 64));
            tmax4[r] = tm;
            need = need || (tm > mrow[r] + 8.f);
        }
        if (__any(need)) {      // rescale path (rare after warmup: defer-max THR=8)
            float a4[4];
            #pragma unroll
            for (int r = 0; r < 4; ++r) {
                float mn = fmaxf(mrow[r], tmax4[r]);
                a4[r] = __expf(mrow[r] - mn);
                mrow[r] = mn;
                lsum[r] *= a4[r];
            }
            #pragma unroll
            for (int i = 0; i < 16; ++i) {
                #pragma unroll
                for (int r = 0; r < 4; ++r) O[i][r] *= a4[r];
            }
        }
        const int prow = g * 4;
        #pragma unroll
        for (int r = 0; r < 4; ++r) {
            float ps = 0.f;
            #pragma unroll
            for (int s = 0; s < 4; ++s) {
                float p = __expf(S[s][r] - mrow[r]);
                ps += p;
                sP[w][prow + r][s * 16 + l15] = (_Float16)p;
            }
            lsum[r] += ps;
        }
        // order the same-wave LDS RAW at compile time and run time (rule #18)
        asm volatile("s_waitcnt lgkmcnt(0)" ::: "memory");
        __builtin_amdgcn_sched_barrier(0);

        // ---- O += P @ V ----
        f16x8 pa0 = *(const f16x8*)&sP[w][l15][khalf];
        f16x8 pa1 = *(const f16x8*)&sP[w][l15][32 + khalf];
        __builtin_amdgcn_s_setprio(1);
        #pragma unroll
        for (int i = 0; i < 16; ++i) {
            f16x8 vb0 = *(const f16x8*)&sVt[i * 16 + l15][khalf];
            f16x8 vb1 = *(const f16x8*)&sVt[i * 16 + l15][32 + khalf];
            O[i] = MFMA_F16(pa0, vb0, O[i]);
            O[i] = MFMA_F16(pa1, vb1, O[i]);
        }
        __builtin_amdgcn_s_setprio(0);
    };

    if constexpr (PREP) {
        loadRegs(0);
        writeLDS();
        __syncthreads();
        for (int ti = 0; ti < NT; ++ti) {
            if (ti + 1 < NT) loadRegs((ti + 1) * BK);   // in flight during compute
            compute();
            __syncthreads();                            // all reads of LDS done
            if (ti + 1 < NT) writeLDS();                // vmcnt waits inserted here
            __syncthreads();                            // LDS ready
        }
    } else {
        const int fr = t & 63, fc = (t >> 6) * 64;
        for (int ti = 0; ti < NT; ++ti) {
            const int m0 = ti * BK;
            __syncthreads();
            #pragma unroll
            for (int e = 0; e < 64; e += 4) {
                float4 kv = *(const float4*)&ksrc[(size_t)(m0 + fr) * Cc + fc + e];
                sK[fr][fc + e + 0] = (_Float16)kv.x; sK[fr][fc + e + 1] = (_Float16)kv.y;
                sK[fr][fc + e + 2] = (_Float16)kv.z; sK[fr][fc + e + 3] = (_Float16)kv.w;
                float4 xv = *(const float4*)&qsrc[(size_t)(m0 + fr) * Cc + fc + e];
                sVt[fc + e + 0][fr] = (_Float16)xv.x; sVt[fc + e + 1][fr] = (_Float16)xv.y;
                sVt[fc + e + 2][fr] = (_Float16)xv.z; sVt[fc + e + 3][fr] = (_Float16)xv.w;
            }
            __syncthreads();
            compute();
        }
    }

    // ---- epilogue: final sum-reduce, normalize, gamma*out + residual ----
    const float gma = gamma_p[0];
    #pragma unroll
    for (int r = 0; r < 4; ++r) {
        float lv = lsum[r];
        #pragma unroll
        for (int off = 8; off >= 1; off >>= 1)
            lv += __shfl_xor(lv, off, 64);
        const float inv = 1.f / lv;
        const int row = qtile * BQ + w * 16 + g * 4 + r;
        const size_t ro = (size_t)row * Cc + l15;
        #pragma unroll
        for (int i = 0; i < 16; ++i) {
            float o = O[i][r] * inv;
            outp[ro + i * 16] = gma * o + qsrc[ro + i * 16];
        }
    }
}

extern "C" void kernel_launch(void* const* d_in, const int* in_sizes, int n_in,
                              void* d_out, int out_size, void* d_ws, size_t ws_size,
                              hipStream_t stream) {
    (void)in_sizes; (void)n_in; (void)out_size;
    const float* xa = (const float*)d_in[0];
    const float* xb = (const float*)d_in[1];
    const float* gm = (const float*)d_in[2];
    float* out = (float*)d_out;

    dim3 agrid(Nn / BQ, Bb, 2);
    if (ws_size >= WS_NEED) {
        _Float16* hi = (_Float16*)d_ws;
        _Float16* lo = hi + ASZ;
        _Float16* vt = lo + ASZ;
        prep_kernel<<<dim3(Nn / 64, Cc / 64, 2 * Bb), 256, 0, stream>>>(xa, xb, hi, lo, vt);
        attn_kernel<true><<<agrid, 256, 0, stream>>>(xa, xb, gm, out, hi, lo, vt);
    } else {
        attn_kernel<false><<<agrid, 256, 0, stream>>>(xa, xb, gm, out, nullptr, nullptr, nullptr);
    }
}

// Round 2
// 338.135 us; speedup vs baseline: 2.3827x; 2.3827x over previous
//
#include <hip/hip_runtime.h>
#include <hip/hip_bf16.h>
#include <stdint.h>

typedef _Float16 f16x8 __attribute__((ext_vector_type(8)));
typedef float f32x4 __attribute__((ext_vector_type(4)));

#define MFMA_F16(A, B, C) __builtin_amdgcn_mfma_f32_16x16x32_f16(A, B, C, 0, 0, 0)

constexpr int Bb = 4, Nn = 4096, Cc = 256;
constexpr int BQ = 128;          // q rows per block (8 waves x 16)
constexpr int BK = 64;           // k/v rows per tile
constexpr int NT = Nn / BK;
constexpr int KPAD = 256;        // 512B row stride (0 mod 128B) + XOR swizzle
constexpr int VPAD = 64;         // 128B row stride (0 mod 128B) + XOR swizzle
constexpr int PPAD = 72;

constexpr size_t ASZ = (size_t)2 * Bb * Nn * Cc;     // elems per ws array
constexpr size_t WS_NEED = ASZ * 2 * 3;              // bytes: hi + lo + vt

// ---------------- prep: fp32 -> fp16 hi/lo + transposed hi ----------------
__global__ __launch_bounds__(256)
void prep_kernel(const float* __restrict__ xa, const float* __restrict__ xb,
                 _Float16* __restrict__ hi, _Float16* __restrict__ lo,
                 _Float16* __restrict__ vt)
{
    const int n0 = blockIdx.x * 64, c0 = blockIdx.y * 64, ib = blockIdx.z;
    const float* x = ((ib >> 2) == 0 ? xa : xb) + (size_t)(ib & 3) * Nn * Cc;
    const size_t base = (size_t)ib * Nn * Cc;
    __shared__ ushort tile[64][68];
    const int t = threadIdx.x;
    const int r0 = t >> 4;            // 0..15
    const int c4 = (t & 15) * 4;      // 0,4,..,60
    #pragma unroll
    for (int ii = 0; ii < 4; ++ii) {
        const int r = r0 + ii * 16;
        float4 v = *(const float4*)&x[(size_t)(n0 + r) * Cc + c0 + c4];
        float vv[4] = {v.x, v.y, v.z, v.w};
        union { _Float16 h[4]; uint2 q; } H, L;
        #pragma unroll
        for (int e = 0; e < 4; ++e) {
            _Float16 h = (_Float16)vv[e];
            H.h[e] = h;
            L.h[e] = (_Float16)(vv[e] - (float)h);
        }
        *(uint2*)&hi[base + (size_t)(n0 + r) * Cc + c0 + c4] = H.q;
        *(uint2*)&lo[base + (size_t)(n0 + r) * Cc + c0 + c4] = L.q;
        *(uint2*)&tile[r][c4] = H.q;
    }
    __syncthreads();
    const int j4 = (t & 15) * 4;
    #pragma unroll
    for (int ii = 0; ii < 4; ++ii) {
        const int cr = r0 + ii * 16;
        ushort4 o;
        o.x = tile[j4 + 0][cr]; o.y = tile[j4 + 1][cr];
        o.z = tile[j4 + 2][cr]; o.w = tile[j4 + 3][cr];
        *(ushort4*)&vt[base + (size_t)(c0 + cr) * Nn + n0 + j4] = o;
    }
}

// ---------------- main attention ----------------
template<bool PREP>
__global__ __launch_bounds__(512, 1)
void attn_kernel(const float* __restrict__ xa, const float* __restrict__ xb,
                 const float* __restrict__ gamma_p, float* __restrict__ out,
                 const _Float16* __restrict__ hi, const _Float16* __restrict__ lo,
                 const _Float16* __restrict__ vt)
{
    const int qtile = blockIdx.x, b = blockIdx.y, dir = blockIdx.z;
    const float* qsrc = (dir == 0 ? xa : xb) + (size_t)b * Nn * Cc;
    const float* ksrc = (dir == 0 ? xb : xa) + (size_t)b * Nn * Cc;
    float* outp = out + (size_t)dir * Bb * Nn * Cc + (size_t)b * Nn * Cc;
    const int qib = dir * Bb + b;
    const int kib = (dir ^ 1) * Bb + b;
    const _Float16* qhiB = hi + (size_t)qib * Nn * Cc;
    const _Float16* qloB = lo + (size_t)qib * Nn * Cc;
    const _Float16* kB   = hi + (size_t)kib * Nn * Cc;
    const _Float16* vtB  = vt + (size_t)qib * Nn * Cc;   // V^T of q-source

    __shared__ _Float16 sK[BK][KPAD];       // K (fp16 hi), rows m; XOR-swizzled
    __shared__ _Float16 sVt[Cc][VPAD];      // sVt[c][m] = V[m][c]; XOR-swizzled
    __shared__ _Float16 sP[8][16][PPAD];    // per-wave P tile [qrow][m]

    const int t = threadIdx.x, lane = t & 63, w = t >> 6;
    const int l15 = lane & 15, g = lane >> 4;
    const int khalf = g * 8;
    const int rsw = (l15 & 7) << 3;         // read swizzle: rows s*16+l15 / c=i*16+l15

    // ---- Q fragments, negated (MFMA yields logits = -E), fp16 hi/lo ----
    f16x8 qhi[8], qlo[8];
    const int qrow = qtile * BQ + w * 16 + l15;
    if constexpr (PREP) {
        #pragma unroll
        for (int j = 0; j < 8; ++j) {
            union { uint4 u; f16x8 h; } A, C2;
            A.u  = *(const uint4*)(qhiB + (size_t)qrow * Cc + j * 32 + khalf);
            C2.u = *(const uint4*)(qloB + (size_t)qrow * Cc + j * 32 + khalf);
            A.u.x ^= 0x80008000u; A.u.y ^= 0x80008000u; A.u.z ^= 0x80008000u; A.u.w ^= 0x80008000u;
            C2.u.x ^= 0x80008000u; C2.u.y ^= 0x80008000u; C2.u.z ^= 0x80008000u; C2.u.w ^= 0x80008000u;
            qhi[j] = A.h; qlo[j] = C2.h;
        }
    } else {
        const float* qb = qsrc + (size_t)qrow * Cc;
        #pragma unroll
        for (int j = 0; j < 8; ++j) {
            float4 v0 = *(const float4*)(qb + j * 32 + khalf);
            float4 v1 = *(const float4*)(qb + j * 32 + khalf + 4);
            float xv[8] = {v0.x, v0.y, v0.z, v0.w, v1.x, v1.y, v1.z, v1.w};
            #pragma unroll
            for (int e = 0; e < 8; ++e) {
                float xn = -xv[e];
                _Float16 h = (_Float16)xn;
                qhi[j][e] = h;
                qlo[j][e] = (_Float16)(xn - (float)h);
            }
        }
    }

    f32x4 O[16];
    #pragma unroll
    for (int i = 0; i < 16; ++i) O[i] = (f32x4){0.f, 0.f, 0.f, 0.f};
    float mrow[4] = {-INFINITY, -INFINITY, -INFINITY, -INFINITY};
    float lsum[4] = {0.f, 0.f, 0.f, 0.f};

    // staging maps (512 threads, round-0 shape: 4 uint4 per thread per array)
    const int kr = t & 63, kc = (t >> 6) * 32;     // K: row, col-chunk (8 waves x 32)
    const int vr = t >> 1, vmc = (t & 1) * 32;     // Vt: row(c), m-chunk
    const int ksw = (kr & 7) << 3;                 // write swizzles
    const int vsw = (vr & 7) << 3;
    uint4 kreg[4], vreg[4];

    auto loadRegs = [&](int m0) {
        const _Float16* kg = kB + (size_t)(m0 + kr) * Cc + kc;
        #pragma unroll
        for (int q = 0; q < 4; ++q) kreg[q] = *(const uint4*)(kg + q * 8);
        const _Float16* vg = vtB + (size_t)vr * Nn + m0 + vmc;
        #pragma unroll
        for (int q = 0; q < 4; ++q) vreg[q] = *(const uint4*)(vg + q * 8);
    };
    auto writeLDS = [&]() {
        #pragma unroll
        for (int q = 0; q < 4; ++q) *(uint4*)&sK[kr][(kc + q * 8) ^ ksw] = kreg[q];
        #pragma unroll
        for (int q = 0; q < 4; ++q) *(uint4*)&sVt[vr][(vmc + q * 8) ^ vsw] = vreg[q];
    };

    auto compute = [&]() {
        // ---- S = (-Q) K^T : q split fp16 hi/lo, k single fp16 ----
        f32x4 S[4];
        #pragma unroll
        for (int s = 0; s < 4; ++s) S[s] = (f32x4){0.f, 0.f, 0.f, 0.f};
        __builtin_amdgcn_s_setprio(1);
        #pragma unroll
        for (int j = 0; j < 8; ++j) {
            const int ko = j * 32 + khalf;
            f16x8 k0 = *(const f16x8*)&sK[l15][ko ^ rsw];
            f16x8 k1 = *(const f16x8*)&sK[16 + l15][ko ^ rsw];
            f16x8 k2 = *(const f16x8*)&sK[32 + l15][ko ^ rsw];
            f16x8 k3 = *(const f16x8*)&sK[48 + l15][ko ^ rsw];
            S[0] = MFMA_F16(qhi[j], k0, S[0]);
            S[1] = MFMA_F16(qhi[j], k1, S[1]);
            S[2] = MFMA_F16(qhi[j], k2, S[2]);
            S[3] = MFMA_F16(qhi[j], k3, S[3]);
            S[0] = MFMA_F16(qlo[j], k0, S[0]);
            S[1] = MFMA_F16(qlo[j], k1, S[1]);
            S[2] = MFMA_F16(qlo[j], k2, S[2]);
            S[3] = MFMA_F16(qlo[j], k3, S[3]);
        }
        __builtin_amdgcn_s_setprio(0);

        // ---- online softmax: per-tile max reduce; sum deferred to epilogue ----
        float tmax4[4];
        bool need = false;
        #pragma unroll
        for (int r = 0; r < 4; ++r) {
            float tm = fmaxf(fmaxf(S[0][r], S[1][r]), fmaxf(S[2][r], S[3][r]));
            #pragma unroll
            for (int off = 8; off >= 1; off >>= 1)
                tm = fmaxf(tm, __shfl_xor(tm, off, 64));
            tmax4[r] = tm;
            need = need || (tm > mrow[r] + 8.f);
        }
        if (__any(need)) {      // rescale path (rare after warmup: defer-max THR=8)
            float a4[4];
            #pragma unroll
            for (int r = 0; r < 4; ++r) {
                float mn = fmaxf(mrow[r], tmax4[r]);
                a4[r] = __expf(mrow[r] - mn);
                mrow[r] = mn;
                lsum[r] *= a4[r];
            }
            #pragma unroll
            for (int i = 0; i < 16; ++i) {
                #pragma unroll
                for (int r = 0; r < 4; ++r) O[i][r] *= a4[r];
            }
        }
        const int prow = g * 4;
        #pragma unroll
        for (int r = 0; r < 4; ++r) {
            float ps = 0.f;
            #pragma unroll
            for (int s = 0; s < 4; ++s) {
                float p = __expf(S[s][r] - mrow[r]);
                ps += p;
                sP[w][prow + r][s * 16 + l15] = (_Float16)p;
            }
            lsum[r] += ps;
        }
        // order the same-wave LDS RAW at compile time and run time (rule #18)
        asm volatile("s_waitcnt lgkmcnt(0)" ::: "memory");
        __builtin_amdgcn_sched_barrier(0);

        // ---- O += P @ V ----
        f16x8 pa0 = *(const f16x8*)&sP[w][l15][khalf];
        f16x8 pa1 = *(const f16x8*)&sP[w][l15][32 + khalf];
        __builtin_amdgcn_s_setprio(1);
        #pragma unroll
        for (int i = 0; i < 16; ++i) {
            f16x8 vb0 = *(const f16x8*)&sVt[i * 16 + l15][khalf ^ rsw];
            f16x8 vb1 = *(const f16x8*)&sVt[i * 16 + l15][(32 + khalf) ^ rsw];
            O[i] = MFMA_F16(pa0, vb0, O[i]);
            O[i] = MFMA_F16(pa1, vb1, O[i]);
        }
        __builtin_amdgcn_s_setprio(0);
    };

    if constexpr (PREP) {
        loadRegs(0);
        writeLDS();
        __syncthreads();
        for (int ti = 0; ti < NT; ++ti) {
            if (ti + 1 < NT) loadRegs((ti + 1) * BK);   // in flight during compute
            compute();
            __syncthreads();                            // all reads of LDS done
            if (ti + 1 < NT) writeLDS();                // vmcnt waits inserted here
            __syncthreads();                            // LDS ready
        }
    } else {
        const int fr = t & 63, fc = (t >> 6) * 32;
        const int fsw = (fr & 7) << 3;
        for (int ti = 0; ti < NT; ++ti) {
            const int m0 = ti * BK;
            __syncthreads();
            #pragma unroll
            for (int e = 0; e < 32; e += 4) {
                float4 kv = *(const float4*)&ksrc[(size_t)(m0 + fr) * Cc + fc + e];
                sK[fr][(fc + e + 0) ^ fsw] = (_Float16)kv.x;
                sK[fr][(fc + e + 1) ^ fsw] = (_Float16)kv.y;
                sK[fr][(fc + e + 2) ^ fsw] = (_Float16)kv.z;
                sK[fr][(fc + e + 3) ^ fsw] = (_Float16)kv.w;
                float4 xv = *(const float4*)&qsrc[(size_t)(m0 + fr) * Cc + fc + e];
                sVt[fc + e + 0][fr ^ (((fc + e + 0) & 7) << 3)] = (_Float16)xv.x;
                sVt[fc + e + 1][fr ^ (((fc + e + 1) & 7) << 3)] = (_Float16)xv.y;
                sVt[fc + e + 2][fr ^ (((fc + e + 2) & 7) << 3)] = (_Float16)xv.z;
                sVt[fc + e + 3][fr ^ (((fc + e + 3) & 7) << 3)] = (_Float16)xv.w;
            }
            __syncthreads();
            compute();
        }
    }

    // ---- epilogue: final sum-reduce, normalize, gamma*out + residual ----
    const float gma = gamma_p[0];
    #pragma unroll
    for (int r = 0; r < 4; ++r) {
        float lv = lsum[r];
        #pragma unroll
        for (int off = 8; off >= 1; off >>= 1)
            lv += __shfl_xor(lv, off, 64);
        const float inv = 1.f / lv;
        const int row = qtile * BQ + w * 16 + g * 4 + r;
        const size_t ro = (size_t)row * Cc + l15;
        #pragma unroll
        for (int i = 0; i < 16; ++i) {
            float o = O[i][r] * inv;
            outp[ro + i * 16] = gma * o + qsrc[ro + i * 16];
        }
    }
}

extern "C" void kernel_launch(void* const* d_in, const int* in_sizes, int n_in,
                              void* d_out, int out_size, void* d_ws, size_t ws_size,
                              hipStream_t stream) {
    (void)in_sizes; (void)n_in; (void)out_size;
    const float* xa = (const float*)d_in[0];
    const float* xb = (const float*)d_in[1];
    const float* gm = (const float*)d_in[2];
    float* out = (float*)d_out;

    dim3 agrid(Nn / BQ, Bb, 2);
    if (ws_size >= WS_NEED) {
        _Float16* hi = (_Float16*)d_ws;
        _Float16* lo = hi + ASZ;
        _Float16* vt = lo + ASZ;
        prep_kernel<<<dim3(Nn / 64, Cc / 64, 2 * Bb), 256, 0, stream>>>(xa, xb, hi, lo, vt);
        attn_kernel<true><<<agrid, 512, 0, stream>>>(xa, xb, gm, out, hi, lo, vt);
    } else {
        attn_kernel<false><<<agrid, 512, 0, stream>>>(xa, xb, gm, out, nullptr, nullptr, nullptr);
    }
}